// Round 14
// baseline (258.778 us; speedup 1.0000x reference)
//
#include <hip/hip_runtime.h>
#include <hip/hip_fp16.h>
#include <math.h>

#define TPB 256
#define NPB 512          // nodes per bucket (power of 2)
#define NPB_SHIFT 9
#define EPB 8192         // edges per phase-A chunk (= one block's private segment)
#define EPW 16           // EPB / 512 threads
#define BCAP 12288       // per-bucket col-window capacity (mean ~8192, +45 sigma)
#define RSTRIDE 32       // packed node record: 16B fp8 row + 4B norm + 12B pad

typedef float v2f __attribute__((ext_vector_type(2)));

__device__ __forceinline__ float leaky_relu(float v) { return v > 0.0f ? v : 0.01f * v; }

__device__ __forceinline__ float dot4(float4 a, float4 b) {
    return a.x * b.x + a.y * b.y + a.z * b.z + a.w * b.w;
}
__device__ __forceinline__ float4 f4_scale(float4 a, float s) {
    return make_float4(a.x * s, a.y * s, a.z * s, a.w * s);
}
// a += w*y
__device__ __forceinline__ float4 f4_acc(float4 a, float w, float4 y) {
    return make_float4(fmaf(w, y.x, a.x), fmaf(w, y.y, a.y),
                       fmaf(w, y.z, a.z), fmaf(w, y.w, a.w));
}
__device__ __forceinline__ float4 f4_add_shfl(float4 v, int d) {
    return make_float4(v.x + __shfl_xor(v.x, d, 64), v.y + __shfl_xor(v.y, d, 64),
                       v.z + __shfl_xor(v.z, d, 64), v.w + __shfl_xor(v.w, d, 64));
}
__device__ __forceinline__ float4 leaky4(float4 v) {
    return make_float4(leaky_relu(v.x), leaky_relu(v.y), leaky_relu(v.z), leaky_relu(v.w));
}

// HW fp8 e4m3 (OCP) pack/unpack: 4 elements <-> one dword
__device__ __forceinline__ float4 dec4(unsigned w) {
    v2f lo = __builtin_amdgcn_cvt_pk_f32_fp8((int)w, false);
    v2f hi = __builtin_amdgcn_cvt_pk_f32_fp8((int)w, true);
    return make_float4(lo.x, lo.y, hi.x, hi.y);
}
__device__ __forceinline__ unsigned enc4(float4 v) {
    int r = __builtin_amdgcn_cvt_pk_fp8_f32(v.x, v.y, 0, false);
    r = __builtin_amdgcn_cvt_pk_fp8_f32(v.z, v.w, r, true);
    return (unsigned)r;
}

// fp16 store helper (conv2 -> MLP rows)
__device__ __forceinline__ void store_h4(__half* row, int l, float4 v) {
    union { float2 f; __half h[4]; } u;
    u.h[0] = __float2half(v.x); u.h[1] = __float2half(v.y);
    u.h[2] = __float2half(v.z); u.h[3] = __float2half(v.w);
    ((float2*)row)[l] = u.f;
}

// packed-record accessors (base is char*, record i at i*RSTRIDE)
__device__ __forceinline__ uint4 rec_q(const char* base, int i) {
    return *(const uint4*)(base + (size_t)i * RSTRIDE);
}
__device__ __forceinline__ float rec_n(const char* base, int i) {
    return *(const float*)(base + (size_t)i * RSTRIDE + 16);
}

// wave-level inclusive scan (64 lanes, shuffle ladder — no barriers)
__device__ __forceinline__ int wave_incl_scan(int v, int lane) {
#pragma unroll
    for (int off = 1; off < 64; off <<= 1) {
        int u = __shfl_up(v, off, 64);
        if (lane >= off) v += u;
    }
    return v;
}

// ---------------- build phase A (+ fused prep) ----------------
__global__ void k_binA(const int* __restrict__ src, const int* __restrict__ dst,
                       unsigned* __restrict__ bdata, int* __restrict__ cbase,
                       int* __restrict__ ccnt, int E, int K,
                       const float* __restrict__ x, char* __restrict__ xqn,
                       int N) {
    __shared__ int hist[512];
    __shared__ unsigned lcol[EPB];   // 32 KB
    __shared__ int wsum[8];
    int t = threadIdx.x;
    int lane = t & 63, wv = t >> 6;
    int c = blockIdx.x;
    int e0 = c * EPB;
    int e1 = min(e0 + EPB, E);
    int tot = e1 - e0;
    hist[t] = 0;
    __syncthreads();
    int myd[EPW], mys[EPW];
    if (tot == EPB) {
        const int4* d4 = (const int4*)(dst + e0);
        const int4* s4 = (const int4*)(src + e0);
#pragma unroll
        for (int k = 0; k < 4; ++k) {
            int4 dd = d4[t + k * 512];
            int4 ss = s4[t + k * 512];
            myd[4 * k + 0] = dd.x; myd[4 * k + 1] = dd.y;
            myd[4 * k + 2] = dd.z; myd[4 * k + 3] = dd.w;
            mys[4 * k + 0] = ss.x; mys[4 * k + 1] = ss.y;
            mys[4 * k + 2] = ss.z; mys[4 * k + 3] = ss.w;
            atomicAdd(&hist[dd.x >> NPB_SHIFT], 1);
            atomicAdd(&hist[dd.y >> NPB_SHIFT], 1);
            atomicAdd(&hist[dd.z >> NPB_SHIFT], 1);
            atomicAdd(&hist[dd.w >> NPB_SHIFT], 1);
        }
    } else {
#pragma unroll
        for (int k = 0; k < EPW; ++k) {
            int e = e0 + t + k * 512;
            int d = (e < e1) ? dst[e] : -1;
            mys[k] = (e < e1) ? src[e] : 0;
            myd[k] = d;
            if (d >= 0) atomicAdd(&hist[d >> NPB_SHIFT], 1);
        }
    }
    __syncthreads();
    int v = hist[t];
    int inc = wave_incl_scan(v, lane);
    if (lane == 63) wsum[wv] = inc;
    __syncthreads();
    if (t == 0) {
        int acc = 0;
#pragma unroll
        for (int k = 0; k < 8; ++k) { int xv = wsum[k]; wsum[k] = acc; acc += xv; }
    }
    __syncthreads();
    int excl = inc + wsum[wv] - v;
    if (t < K) {
        cbase[(size_t)c * K + t] = excl;
        ccnt[(size_t)c * K + t] = v;
    }
    __syncthreads();
    hist[t] = excl;   // reuse as cursor
    __syncthreads();
    if (tot == EPB) {
#pragma unroll
        for (int k = 0; k < EPW; ++k) {
            int d = myd[k];
            int p = atomicAdd(&hist[d >> NPB_SHIFT], 1);
            lcol[p] = ((unsigned)(d & (NPB - 1)) << 18) | (unsigned)mys[k];
        }
    } else {
#pragma unroll
        for (int k = 0; k < EPW; ++k) {
            int d = myd[k];
            if (d >= 0) {
                int p = atomicAdd(&hist[d >> NPB_SHIFT], 1);
                lcol[p] = ((unsigned)(d & (NPB - 1)) << 18) | (unsigned)mys[k];
            }
        }
    }
    __syncthreads();
    unsigned* outp = bdata + (size_t)c * EPB;
    for (int i = t; i < tot; i += 512) outp[i] = lcol[i];
    // ---- fused prep: packed record ----
    int i = c * 512 + t;
    if (i < N) {
        const float4* xp = (const float4*)(x + (size_t)i * 16);
        float4 a = xp[0], b = xp[1], cc = xp[2], d = xp[3];
        float ss = dot4(a, a) + dot4(b, b) + dot4(cc, cc) + dot4(d, d);
        float nn = fmaxf(sqrtf(ss), 1e-12f);
        float inv = 1.0f / nn;
        char* rp = xqn + (size_t)i * RSTRIDE;
        *(uint4*)rp = make_uint4(enc4(f4_scale(a, inv)), enc4(f4_scale(b, inv)),
                                 enc4(f4_scale(cc, inv)), enc4(f4_scale(d, inv)));
        *(float*)(rp + 16) = nn;
    }
}

// ---------------- build phase B: per-bucket CSR, thread-per-run ----------------
__global__ void k_binB(const unsigned* __restrict__ bdata, const int* __restrict__ cbase,
                       const int* __restrict__ ccnt,
                       int* __restrict__ startp, int* __restrict__ endp,
                       int* __restrict__ col, int N, int NC, int K) {
    __shared__ int cb[512];
    __shared__ int cc[512];
    __shared__ int ldeg[NPB];
    __shared__ int wsum[8];
    int b = blockIdx.x, t = threadIdx.x;
    int lane = t & 63, wv = t >> 6;
    int n0 = b << NPB_SHIFT;
    int nn = min(NPB, N - n0);
    cb[t] = (t < NC) ? cbase[(size_t)t * K + b] : 0;
    cc[t] = (t < NC) ? ccnt[(size_t)t * K + b] : 0;
    ldeg[t] = 0;
    __syncthreads();
    int mycnt = (t < NC) ? cc[t] : 0;
    const unsigned* myp = bdata + (size_t)t * EPB + cb[t];
    for (int k = 0; k < mycnt; ++k) {
        unsigned e = myp[k];
        atomicAdd(&ldeg[e >> 18], 1);
    }
    __syncthreads();
    int dv = ldeg[t];
    int inc = wave_incl_scan(dv, lane);
    if (lane == 63) wsum[wv] = inc;
    __syncthreads();
    if (t == 0) {
        int acc = 0;
#pragma unroll
        for (int k = 0; k < 8; ++k) { int xv = wsum[k]; wsum[k] = acc; acc += xv; }
    }
    __syncthreads();
    int excl = inc + wsum[wv] - dv;
    int gb = b * BCAP;
    if (t < nn) {
        startp[n0 + t] = gb + excl;
        endp[n0 + t] = gb + excl + dv;
    }
    __syncthreads();
    ldeg[t] = excl;   // cursor
    __syncthreads();
    for (int k = 0; k < mycnt; ++k) {
        unsigned e = myp[k];
        int pos = atomicAdd(&ldeg[e >> 18], 1);
        col[gb + pos] = (int)(e & 0x3FFFFu);
    }
}

// ---------------- AGNN conv: 16 lanes per node, full row per lane ----------------
// Lane-widening is the one conv change that has worked (4->8 lanes, round 12):
// the wave-serial trip count is the binding term. 16 lanes -> ~2 trips incl.
// Poisson tail. Clamped tail loads hit one broadcast line. 4-step butterfly.
__global__ void k_agnn(const char* __restrict__ xqn,
                       const int* __restrict__ startp, const int* __restrict__ endp,
                       const int* __restrict__ col,
                       const float* __restrict__ beta_ptr, int beta_idx,
                       void* __restrict__ out, int n, int fp8_out) {
    int t = threadIdx.x;
    int l = t & 15;
    int i = blockIdx.x * (512 / 16) + (t >> 4);
    if (i >= n) return;
    float bet = beta_ptr[beta_idx];
    uint4 rowi = rec_q(xqn, i);
    float ni = rec_n(xqn, i);
    float4 x0 = dec4(rowi.x), x1 = dec4(rowi.y), x2 = dec4(rowi.z), x3 = dec4(rowi.w);
    float4 q0 = f4_scale(x0, bet), q1 = f4_scale(x1, bet),
           q2 = f4_scale(x2, bet), q3 = f4_scale(x3, bet);
    float s;
    float4 a0, a1, a2, a3;
    if (l == 0) {
        float aself = dot4(x0, q0) + dot4(x1, q1) + dot4(x2, q2) + dot4(x3, q3);
        float w = __expf(aself);
        s = w;
        float wi = w * ni;
        a0 = f4_scale(x0, wi); a1 = f4_scale(x1, wi);
        a2 = f4_scale(x2, wi); a3 = f4_scale(x3, wi);
    } else {
        s = 0.0f;
        a0 = a1 = a2 = a3 = make_float4(0.f, 0.f, 0.f, 0.f);
    }
    int e1 = endp[i];
    int last = max(e1 - 1, 0);
    int e = startp[i] + l;
    int j0 = min(max(col[min(e, last)], 0), n - 1);
    uint4 rA = rec_q(xqn, j0);
    float nA = rec_n(xqn, j0);
    int j1 = min(max(col[min(e + 16, last)], 0), n - 1);
    uint4 rB = rec_q(xqn, j1);
    float nB = rec_n(xqn, j1);
    for (; e < e1; e += 16) {
        int j2 = min(max(col[min(e + 32, last)], 0), n - 1);
        uint4 rC = rec_q(xqn, j2);
        float nC = rec_n(xqn, j2);
        float4 y0 = dec4(rA.x), y1 = dec4(rA.y), y2 = dec4(rA.z), y3 = dec4(rA.w);
        float d = dot4(y0, q0) + dot4(y1, q1) + dot4(y2, q2) + dot4(y3, q3);
        float w = __expf(d);
        s += w;
        float wn = w * nA;
        a0 = f4_acc(a0, wn, y0);
        a1 = f4_acc(a1, wn, y1);
        a2 = f4_acc(a2, wn, y2);
        a3 = f4_acc(a3, wn, y3);
        rA = rB; nA = nB; rB = rC; nB = nC;
    }
    // merge 16 lane-states: plain sums (butterfly; groups 16-aligned)
#pragma unroll
    for (int d_ = 1; d_ < 16; d_ <<= 1) {
        s += __shfl_xor(s, d_, 64);
        a0 = f4_add_shfl(a0, d_);
        a1 = f4_add_shfl(a1, d_);
        a2 = f4_add_shfl(a2, d_);
        a3 = f4_add_shfl(a3, d_);
    }
    float inv = 1.0f / (s + 1e-16f);
    float4 o0 = leaky4(f4_scale(a0, inv));
    float4 o1 = leaky4(f4_scale(a1, inv));
    float4 o2 = leaky4(f4_scale(a2, inv));
    float4 o3 = leaky4(f4_scale(a3, inv));
    if (l < 4) {
        float4 oq = (l == 0) ? o0 : (l == 1) ? o1 : (l == 2) ? o2 : o3;
        if (fp8_out) {
            float ss = dot4(o0, o0) + dot4(o1, o1) + dot4(o2, o2) + dot4(o3, o3);
            float nn = fmaxf(sqrtf(ss), 1e-12f);
            char* rp = (char*)out + (size_t)i * RSTRIDE;
            ((unsigned*)rp)[l] = enc4(f4_scale(oq, 1.0f / nn));
            if (l == 0) *(float*)(rp + 16) = nn;
        } else {
            store_h4((__half*)out + (size_t)i * 16, l, oq);
        }
    }
}

// ---------------- MLP head + fused per-block logsumexp partials ----------------
// Row gathers as 2x uint4 (was 4x float2 per row): halves gather instructions.
__global__ void k_mlp(const __half* __restrict__ x, const int* __restrict__ home,
                      const int* __restrict__ away,
                      const float* __restrict__ w0, const float* __restrict__ b0,
                      const float* __restrict__ w1, const float* __restrict__ b1,
                      const float* __restrict__ w2, const float* __restrict__ b2,
                      float* __restrict__ z, float* __restrict__ bmax,
                      float* __restrict__ bsum, int nb) {
    __shared__ float sw0[192], sw1[96], sw2[48], sb0[6], sb1[16], sb2[3];
    __shared__ float rmax[4][3];
    __shared__ float rsum[4][3];
    int t = threadIdx.x;
    if (t < 192) sw0[t] = w0[t];
    if (t < 96)  sw1[t] = w1[t];
    if (t < 48)  sw2[t] = w2[t];
    if (t < 6)   sb0[t] = b0[t];
    if (t < 16)  sb1[t] = b1[t];
    if (t < 3)   sb2[t] = b2[t];
    __syncthreads();
    int i = blockIdx.x * blockDim.x + t;
    bool act = i < nb;
    float z0 = -3.4e38f, z1 = -3.4e38f, z2 = -3.4e38f;
    if (act) {
        float h[32];
        const uint4* hr = (const uint4*)(x + (size_t)home[i] * 16);
        const uint4* ar = (const uint4*)(x + (size_t)away[i] * 16);
        uint4 hv0 = hr[0], hv1 = hr[1];
        uint4 av0 = ar[0], av1 = ar[1];
        union { uint4 u; __half2 h2[4]; } cv;
#pragma unroll
        for (int q = 0; q < 4; ++q) {
            cv.u = (q == 0) ? hv0 : (q == 1) ? hv1 : (q == 2) ? av0 : av1;
#pragma unroll
            for (int k = 0; k < 4; ++k) {
                float2 f = __half22float2(cv.h2[k]);
                h[q * 8 + 2 * k + 0] = f.x;
                h[q * 8 + 2 * k + 1] = f.y;
            }
        }
        float t0[6];
#pragma unroll
        for (int o = 0; o < 6; ++o) {
            float acc = sb0[o];
#pragma unroll
            for (int k = 0; k < 32; ++k) acc = fmaf(h[k], sw0[k * 6 + o], acc);
            t0[o] = leaky_relu(acc);
        }
        float t1[16];
#pragma unroll
        for (int o = 0; o < 16; ++o) {
            float acc = sb1[o];
#pragma unroll
            for (int k = 0; k < 6; ++k) acc = fmaf(t0[k], sw1[k * 16 + o], acc);
            t1[o] = leaky_relu(acc);
        }
        float zz[3];
#pragma unroll
        for (int o = 0; o < 3; ++o) {
            float acc = sb2[o];
#pragma unroll
            for (int k = 0; k < 16; ++k) acc = fmaf(t1[k], sw2[k * 3 + o], acc);
            zz[o] = leaky_relu(acc);
            z[(size_t)i * 3 + o] = zz[o];
        }
        z0 = zz[0]; z1 = zz[1]; z2 = zz[2];
    }
    float w0_ = z0, w1_ = z1, w2_ = z2;
#pragma unroll
    for (int off = 32; off > 0; off >>= 1) {
        w0_ = fmaxf(w0_, __shfl_down(w0_, off));
        w1_ = fmaxf(w1_, __shfl_down(w1_, off));
        w2_ = fmaxf(w2_, __shfl_down(w2_, off));
    }
    int wid = t >> 6;
    if ((t & 63) == 0) { rmax[wid][0] = w0_; rmax[wid][1] = w1_; rmax[wid][2] = w2_; }
    __syncthreads();
    float M0 = fmaxf(fmaxf(rmax[0][0], rmax[1][0]), fmaxf(rmax[2][0], rmax[3][0]));
    float M1 = fmaxf(fmaxf(rmax[0][1], rmax[1][1]), fmaxf(rmax[2][1], rmax[3][1]));
    float M2 = fmaxf(fmaxf(rmax[0][2], rmax[1][2]), fmaxf(rmax[2][2], rmax[3][2]));
    float e0 = act ? __expf(z0 - M0) : 0.0f;
    float e1 = act ? __expf(z1 - M1) : 0.0f;
    float e2 = act ? __expf(z2 - M2) : 0.0f;
#pragma unroll
    for (int off = 32; off > 0; off >>= 1) {
        e0 += __shfl_down(e0, off);
        e1 += __shfl_down(e1, off);
        e2 += __shfl_down(e2, off);
    }
    if ((t & 63) == 0) { rsum[wid][0] = e0; rsum[wid][1] = e1; rsum[wid][2] = e2; }
    __syncthreads();
    if (t == 0) {
        float S0 = rsum[0][0] + rsum[1][0] + rsum[2][0] + rsum[3][0];
        float S1 = rsum[0][1] + rsum[1][1] + rsum[2][1] + rsum[3][1];
        float S2 = rsum[0][2] + rsum[1][2] + rsum[2][2] + rsum[3][2];
        bmax[blockIdx.x * 3 + 0] = M0; bmax[blockIdx.x * 3 + 1] = M1; bmax[blockIdx.x * 3 + 2] = M2;
        bsum[blockIdx.x * 3 + 0] = S0; bsum[blockIdx.x * 3 + 1] = S1; bsum[blockIdx.x * 3 + 2] = S2;
    }
}

// merge per-block (max, sumexp) partials -> global per-column
__global__ void k_lse(const float* __restrict__ bmax, const float* __restrict__ bsum,
                      float* __restrict__ gM, float* __restrict__ gS, int nblk) {
    __shared__ float lm[4][3];
    __shared__ float ls[4][3];
    int t = threadIdx.x;
    float M0 = -3.4e38f, M1 = -3.4e38f, M2 = -3.4e38f;
    float S0 = 0.f, S1 = 0.f, S2 = 0.f;
    for (int b = t; b < nblk; b += 256) {
        float m0 = bmax[b * 3 + 0], s0 = bsum[b * 3 + 0];
        float n0 = fmaxf(M0, m0); S0 = S0 * __expf(M0 - n0) + s0 * __expf(m0 - n0); M0 = n0;
        float m1 = bmax[b * 3 + 1], s1 = bsum[b * 3 + 1];
        float n1 = fmaxf(M1, m1); S1 = S1 * __expf(M1 - n1) + s1 * __expf(m1 - n1); M1 = n1;
        float m2 = bmax[b * 3 + 2], s2 = bsum[b * 3 + 2];
        float n2 = fmaxf(M2, m2); S2 = S2 * __expf(M2 - n2) + s2 * __expf(m2 - n2); M2 = n2;
    }
#pragma unroll
    for (int off = 32; off > 0; off >>= 1) {
        float mo, so, nm;
        mo = __shfl_down(M0, off); so = __shfl_down(S0, off);
        nm = fmaxf(M0, mo); S0 = S0 * __expf(M0 - nm) + so * __expf(mo - nm); M0 = nm;
        mo = __shfl_down(M1, off); so = __shfl_down(S1, off);
        nm = fmaxf(M1, mo); S1 = S1 * __expf(M1 - nm) + so * __expf(mo - nm); M1 = nm;
        mo = __shfl_down(M2, off); so = __shfl_down(S2, off);
        nm = fmaxf(M2, mo); S2 = S2 * __expf(M2 - nm) + so * __expf(mo - nm); M2 = nm;
    }
    int wid = t >> 6;
    if ((t & 63) == 0) {
        lm[wid][0] = M0; lm[wid][1] = M1; lm[wid][2] = M2;
        ls[wid][0] = S0; ls[wid][1] = S1; ls[wid][2] = S2;
    }
    __syncthreads();
    if (t == 0) {
        for (int w = 1; w < 4; ++w) {
            float nm;
            nm = fmaxf(M0, lm[w][0]); S0 = S0 * __expf(M0 - nm) + ls[w][0] * __expf(lm[w][0] - nm); M0 = nm;
            nm = fmaxf(M1, lm[w][1]); S1 = S1 * __expf(M1 - nm) + ls[w][1] * __expf(lm[w][1] - nm); M1 = nm;
            nm = fmaxf(M2, lm[w][2]); S2 = S2 * __expf(M2 - nm) + ls[w][2] * __expf(lm[w][2] - nm); M2 = nm;
        }
        gM[0] = M0; gM[1] = M1; gM[2] = M2;
        gS[0] = S0; gS[1] = S1; gS[2] = S2;
    }
}

__device__ __forceinline__ float pick3(int c, float L0, float L1, float L2) {
    return c == 0 ? L0 : (c == 1 ? L1 : L2);
}

// vectorized: 4 floats/thread; component column = (4i+k) % 3
__global__ void k_final(const float4* __restrict__ z4, const float* __restrict__ gM,
                        const float* __restrict__ gS, float4* __restrict__ out4, int n4) {
    int i = blockIdx.x * blockDim.x + threadIdx.x;
    if (i >= n4) return;
    float L0 = gM[0] + logf(gS[0]);
    float L1 = gM[1] + logf(gS[1]);
    float L2 = gM[2] + logf(gS[2]);
    float4 v = z4[i];
    int c = i % 3;                 // (4i)%3 == i%3
    int c1 = (c + 1) % 3, c2 = (c + 2) % 3;
    out4[i] = make_float4(v.x - pick3(c, L0, L1, L2),
                          v.y - pick3(c1, L0, L1, L2),
                          v.z - pick3(c2, L0, L1, L2),
                          v.w - pick3(c, L0, L1, L2));
}

extern "C" void kernel_launch(void* const* d_in, const int* in_sizes, int n_in,
                              void* d_out, int out_size, void* d_ws, size_t ws_size,
                              hipStream_t stream) {
    const float* embed = (const float*)d_in[0];
    const float* beta  = (const float*)d_in[1];
    const float* w0 = (const float*)d_in[2];
    const float* b0 = (const float*)d_in[3];
    const float* w1 = (const float*)d_in[4];
    const float* b1 = (const float*)d_in[5];
    const float* w2 = (const float*)d_in[6];
    const float* b2 = (const float*)d_in[7];
    const int* eidx = (const int*)d_in[8];
    const int* home = (const int*)d_in[9];
    const int* away = (const int*)d_in[10];

    const int N = in_sizes[0] / 16;
    const int E = in_sizes[8] / 2;
    const int B = in_sizes[9];
    const int* esrc = eidx;
    const int* edst = eidx + E;
    const int K = (N + NPB - 1) >> NPB_SHIFT;       // 391 buckets
    const int NC = (E + EPB - 1) / EPB;             // 391 chunks (<=512)

    char* ws = (char*)d_ws;
    size_t off = 0;
    auto alloc = [&](size_t bytes) -> char* {
        off = (off + 255) & ~(size_t)255;
        char* p = ws + off;
        off += bytes;
        return p;
    };
    // union region: bdata (build) aliases {xqn1, zbuf} (both written after binB)
    size_t bdata_bytes = (size_t)NC * EPB * 4;   // 12.8 MB
    size_t alias_bytes = (((size_t)N * RSTRIDE + 511) & ~(size_t)255) + (size_t)B * 3 * 4;
    char* U = alloc(bdata_bytes > alias_bytes ? bdata_bytes : alias_bytes);
    unsigned* bdata = (unsigned*)U;
    char* xqn1  = U;                                                        // N*32B packed
    float* zbuf = (float*)(U + (((size_t)N * RSTRIDE + 511) & ~(size_t)255)); // B*3*4B

    int* startp  = (int*)alloc((size_t)N * 4);
    int* endp    = (int*)alloc((size_t)N * 4);
    int* colw    = (int*)alloc((size_t)K * BCAP * 4);   // padded per-bucket windows
    int* cbase   = (int*)alloc((size_t)NC * K * 4);
    int* ccnt    = (int*)alloc((size_t)NC * K * 4);
    char* xqn0   = alloc((size_t)N * RSTRIDE);
    __half* xh2  = (__half*)alloc((size_t)N * 32);
    const int nblkB = (B + TPB - 1) / TPB;
    float* bmax  = (float*)alloc((size_t)nblkB * 3 * 4);
    float* bsum  = (float*)alloc((size_t)nblkB * 3 * 4);
    float* gM    = (float*)alloc(16);
    float* gS    = (float*)alloc(16);
    (void)ws_size; (void)n_in; (void)out_size;

    k_binA<<<NC, 512, 0, stream>>>(esrc, edst, bdata, cbase, ccnt, E, K,
                                   embed, xqn0, N);
    k_binB<<<K, 512, 0, stream>>>(bdata, cbase, ccnt, startp, endp, colw, N, NC, K);

    const int nblkN16 = (N + 31) / 32;   // 512 threads, 16 lanes/node
    k_agnn<<<nblkN16, 512, 0, stream>>>(xqn0, startp, endp, colw, beta, 0, xqn1, N, 1);
    k_agnn<<<nblkN16, 512, 0, stream>>>(xqn1, startp, endp, colw, beta, 1, xh2, N, 0);

    k_mlp<<<nblkB, TPB, 0, stream>>>(xh2, home, away, w0, b0, w1, b1, w2, b2,
                                     zbuf, bmax, bsum, B);
    k_lse<<<1, 256, 0, stream>>>(bmax, bsum, gM, gS, nblkB);
    const int n4 = (B * 3) / 4;
    k_final<<<(n4 + TPB - 1) / TPB, TPB, 0, stream>>>((const float4*)zbuf, gM, gS,
                                                      (float4*)d_out, n4);
}

// Round 15
// 234.683 us; speedup vs baseline: 1.1027x; 1.1027x over previous
//
#include <hip/hip_runtime.h>
#include <hip/hip_fp16.h>
#include <math.h>

#define TPB 256
#define NPB 512          // nodes per bucket (power of 2)
#define NPB_SHIFT 9
#define EPB 8192         // edges per phase-A chunk (= one block's private segment)
#define EPW 16           // EPB / 512 threads
#define BCAP 12288       // per-bucket col-window capacity (mean ~8192, +45 sigma)
#define RSTRIDE 32       // packed node record: 16B fp8 row + 4B norm + 12B pad

typedef float v2f __attribute__((ext_vector_type(2)));

__device__ __forceinline__ float leaky_relu(float v) { return v > 0.0f ? v : 0.01f * v; }

__device__ __forceinline__ float dot4(float4 a, float4 b) {
    return a.x * b.x + a.y * b.y + a.z * b.z + a.w * b.w;
}
__device__ __forceinline__ float4 f4_scale(float4 a, float s) {
    return make_float4(a.x * s, a.y * s, a.z * s, a.w * s);
}
// a += w*y
__device__ __forceinline__ float4 f4_acc(float4 a, float w, float4 y) {
    return make_float4(fmaf(w, y.x, a.x), fmaf(w, y.y, a.y),
                       fmaf(w, y.z, a.z), fmaf(w, y.w, a.w));
}
__device__ __forceinline__ float4 f4_add_shfl(float4 v, int d) {
    return make_float4(v.x + __shfl_xor(v.x, d, 64), v.y + __shfl_xor(v.y, d, 64),
                       v.z + __shfl_xor(v.z, d, 64), v.w + __shfl_xor(v.w, d, 64));
}
__device__ __forceinline__ float4 leaky4(float4 v) {
    return make_float4(leaky_relu(v.x), leaky_relu(v.y), leaky_relu(v.z), leaky_relu(v.w));
}

// HW fp8 e4m3 (OCP) pack/unpack: 4 elements <-> one dword
__device__ __forceinline__ float4 dec4(unsigned w) {
    v2f lo = __builtin_amdgcn_cvt_pk_f32_fp8((int)w, false);
    v2f hi = __builtin_amdgcn_cvt_pk_f32_fp8((int)w, true);
    return make_float4(lo.x, lo.y, hi.x, hi.y);
}
__device__ __forceinline__ unsigned enc4(float4 v) {
    int r = __builtin_amdgcn_cvt_pk_fp8_f32(v.x, v.y, 0, false);
    r = __builtin_amdgcn_cvt_pk_fp8_f32(v.z, v.w, r, true);
    return (unsigned)r;
}

// fp16 store helper (conv2 -> MLP rows)
__device__ __forceinline__ void store_h4(__half* row, int l, float4 v) {
    union { float2 f; __half h[4]; } u;
    u.h[0] = __float2half(v.x); u.h[1] = __float2half(v.y);
    u.h[2] = __float2half(v.z); u.h[3] = __float2half(v.w);
    ((float2*)row)[l] = u.f;
}

// packed-record accessors (base is char*, record i at i*RSTRIDE)
__device__ __forceinline__ uint4 rec_q(const char* base, int i) {
    return *(const uint4*)(base + (size_t)i * RSTRIDE);
}
__device__ __forceinline__ float rec_n(const char* base, int i) {
    return *(const float*)(base + (size_t)i * RSTRIDE + 16);
}

// wave-level inclusive scan (64 lanes, shuffle ladder — no barriers)
__device__ __forceinline__ int wave_incl_scan(int v, int lane) {
#pragma unroll
    for (int off = 1; off < 64; off <<= 1) {
        int u = __shfl_up(v, off, 64);
        if (lane >= off) v += u;
    }
    return v;
}

// ---------------- build phase A (+ fused prep) ----------------
__global__ void k_binA(const int* __restrict__ src, const int* __restrict__ dst,
                       unsigned* __restrict__ bdata, int* __restrict__ cbase,
                       int* __restrict__ ccnt, int E, int K,
                       const float* __restrict__ x, char* __restrict__ xqn,
                       int N) {
    __shared__ int hist[512];
    __shared__ unsigned lcol[EPB];   // 32 KB
    __shared__ int wsum[8];
    int t = threadIdx.x;
    int lane = t & 63, wv = t >> 6;
    int c = blockIdx.x;
    int e0 = c * EPB;
    int e1 = min(e0 + EPB, E);
    int tot = e1 - e0;
    hist[t] = 0;
    __syncthreads();
    int myd[EPW], mys[EPW];
    if (tot == EPB) {
        const int4* d4 = (const int4*)(dst + e0);
        const int4* s4 = (const int4*)(src + e0);
#pragma unroll
        for (int k = 0; k < 4; ++k) {
            int4 dd = d4[t + k * 512];
            int4 ss = s4[t + k * 512];
            myd[4 * k + 0] = dd.x; myd[4 * k + 1] = dd.y;
            myd[4 * k + 2] = dd.z; myd[4 * k + 3] = dd.w;
            mys[4 * k + 0] = ss.x; mys[4 * k + 1] = ss.y;
            mys[4 * k + 2] = ss.z; mys[4 * k + 3] = ss.w;
            atomicAdd(&hist[dd.x >> NPB_SHIFT], 1);
            atomicAdd(&hist[dd.y >> NPB_SHIFT], 1);
            atomicAdd(&hist[dd.z >> NPB_SHIFT], 1);
            atomicAdd(&hist[dd.w >> NPB_SHIFT], 1);
        }
    } else {
#pragma unroll
        for (int k = 0; k < EPW; ++k) {
            int e = e0 + t + k * 512;
            int d = (e < e1) ? dst[e] : -1;
            mys[k] = (e < e1) ? src[e] : 0;
            myd[k] = d;
            if (d >= 0) atomicAdd(&hist[d >> NPB_SHIFT], 1);
        }
    }
    __syncthreads();
    int v = hist[t];
    int inc = wave_incl_scan(v, lane);
    if (lane == 63) wsum[wv] = inc;
    __syncthreads();
    if (t == 0) {
        int acc = 0;
#pragma unroll
        for (int k = 0; k < 8; ++k) { int xv = wsum[k]; wsum[k] = acc; acc += xv; }
    }
    __syncthreads();
    int excl = inc + wsum[wv] - v;
    if (t < K) {
        cbase[(size_t)c * K + t] = excl;
        ccnt[(size_t)c * K + t] = v;
    }
    __syncthreads();
    hist[t] = excl;   // reuse as cursor
    __syncthreads();
    if (tot == EPB) {
#pragma unroll
        for (int k = 0; k < EPW; ++k) {
            int d = myd[k];
            int p = atomicAdd(&hist[d >> NPB_SHIFT], 1);
            lcol[p] = ((unsigned)(d & (NPB - 1)) << 18) | (unsigned)mys[k];
        }
    } else {
#pragma unroll
        for (int k = 0; k < EPW; ++k) {
            int d = myd[k];
            if (d >= 0) {
                int p = atomicAdd(&hist[d >> NPB_SHIFT], 1);
                lcol[p] = ((unsigned)(d & (NPB - 1)) << 18) | (unsigned)mys[k];
            }
        }
    }
    __syncthreads();
    unsigned* outp = bdata + (size_t)c * EPB;
    for (int i = t; i < tot; i += 512) outp[i] = lcol[i];
    // ---- fused prep: packed record ----
    int i = c * 512 + t;
    if (i < N) {
        const float4* xp = (const float4*)(x + (size_t)i * 16);
        float4 a = xp[0], b = xp[1], cc = xp[2], d = xp[3];
        float ss = dot4(a, a) + dot4(b, b) + dot4(cc, cc) + dot4(d, d);
        float nn = fmaxf(sqrtf(ss), 1e-12f);
        float inv = 1.0f / nn;
        char* rp = xqn + (size_t)i * RSTRIDE;
        *(uint4*)rp = make_uint4(enc4(f4_scale(a, inv)), enc4(f4_scale(b, inv)),
                                 enc4(f4_scale(cc, inv)), enc4(f4_scale(d, inv)));
        *(float*)(rp + 16) = nn;
    }
}

// ---------------- build phase B: per-bucket CSR, thread-per-run ----------------
__global__ void k_binB(const unsigned* __restrict__ bdata, const int* __restrict__ cbase,
                       const int* __restrict__ ccnt,
                       int* __restrict__ startp, int* __restrict__ endp,
                       int* __restrict__ col, int N, int NC, int K) {
    __shared__ int cb[512];
    __shared__ int cc[512];
    __shared__ int ldeg[NPB];
    __shared__ int wsum[8];
    int b = blockIdx.x, t = threadIdx.x;
    int lane = t & 63, wv = t >> 6;
    int n0 = b << NPB_SHIFT;
    int nn = min(NPB, N - n0);
    cb[t] = (t < NC) ? cbase[(size_t)t * K + b] : 0;
    cc[t] = (t < NC) ? ccnt[(size_t)t * K + b] : 0;
    ldeg[t] = 0;
    __syncthreads();
    int mycnt = (t < NC) ? cc[t] : 0;
    const unsigned* myp = bdata + (size_t)t * EPB + cb[t];
    for (int k = 0; k < mycnt; ++k) {
        unsigned e = myp[k];
        atomicAdd(&ldeg[e >> 18], 1);
    }
    __syncthreads();
    int dv = ldeg[t];
    int inc = wave_incl_scan(dv, lane);
    if (lane == 63) wsum[wv] = inc;
    __syncthreads();
    if (t == 0) {
        int acc = 0;
#pragma unroll
        for (int k = 0; k < 8; ++k) { int xv = wsum[k]; wsum[k] = acc; acc += xv; }
    }
    __syncthreads();
    int excl = inc + wsum[wv] - dv;
    int gb = b * BCAP;
    if (t < nn) {
        startp[n0 + t] = gb + excl;
        endp[n0 + t] = gb + excl + dv;
    }
    __syncthreads();
    ldeg[t] = excl;   // cursor
    __syncthreads();
    for (int k = 0; k < mycnt; ++k) {
        unsigned e = myp[k];
        int pos = atomicAdd(&ldeg[e >> 18], 1);
        col[gb + pos] = (int)(e & 0x3FFFFu);
    }
}

// ---------------- AGNN conv: 8 lanes per node, full row per lane ----------------
// Round-12/13 version (best measured). Lane-width curve is 4 < 8 > 16:
// 16 lanes doubled FETCH (clamped-tail duplicate loads + 3x col prefetch
// stream) and VALU jumped to 57% — redundant work beats serial-depth savings
// past 8 lanes at mean degree ~16.
__global__ void k_agnn(const char* __restrict__ xqn,
                       const int* __restrict__ startp, const int* __restrict__ endp,
                       const int* __restrict__ col,
                       const float* __restrict__ beta_ptr, int beta_idx,
                       void* __restrict__ out, int n, int fp8_out) {
    int t = threadIdx.x;
    int l = t & 7;
    int i = blockIdx.x * (512 / 8) + (t >> 3);
    if (i >= n) return;
    float bet = beta_ptr[beta_idx];
    uint4 rowi = rec_q(xqn, i);
    float ni = rec_n(xqn, i);
    float4 x0 = dec4(rowi.x), x1 = dec4(rowi.y), x2 = dec4(rowi.z), x3 = dec4(rowi.w);
    float4 q0 = f4_scale(x0, bet), q1 = f4_scale(x1, bet),
           q2 = f4_scale(x2, bet), q3 = f4_scale(x3, bet);
    float s;
    float4 a0, a1, a2, a3;
    if (l == 0) {
        float aself = dot4(x0, q0) + dot4(x1, q1) + dot4(x2, q2) + dot4(x3, q3);
        float w = __expf(aself);
        s = w;
        float wi = w * ni;
        a0 = f4_scale(x0, wi); a1 = f4_scale(x1, wi);
        a2 = f4_scale(x2, wi); a3 = f4_scale(x3, wi);
    } else {
        s = 0.0f;
        a0 = a1 = a2 = a3 = make_float4(0.f, 0.f, 0.f, 0.f);
    }
    int e1 = endp[i];
    int last = max(e1 - 1, 0);
    int e = startp[i] + l;
    int j0 = min(max(col[min(e, last)], 0), n - 1);
    uint4 rA = rec_q(xqn, j0);
    float nA = rec_n(xqn, j0);
    int j1 = min(max(col[min(e + 8, last)], 0), n - 1);
    uint4 rB = rec_q(xqn, j1);
    float nB = rec_n(xqn, j1);
    for (; e < e1; e += 8) {
        int j2 = min(max(col[min(e + 16, last)], 0), n - 1);
        uint4 rC = rec_q(xqn, j2);
        float nC = rec_n(xqn, j2);
        float4 y0 = dec4(rA.x), y1 = dec4(rA.y), y2 = dec4(rA.z), y3 = dec4(rA.w);
        float d = dot4(y0, q0) + dot4(y1, q1) + dot4(y2, q2) + dot4(y3, q3);
        float w = __expf(d);
        s += w;
        float wn = w * nA;
        a0 = f4_acc(a0, wn, y0);
        a1 = f4_acc(a1, wn, y1);
        a2 = f4_acc(a2, wn, y2);
        a3 = f4_acc(a3, wn, y3);
        rA = rB; nA = nB; rB = rC; nB = nC;
    }
    // merge 8 lane-states: plain sums (butterfly; groups 8-aligned)
#pragma unroll
    for (int d_ = 1; d_ < 8; d_ <<= 1) {
        s += __shfl_xor(s, d_, 64);
        a0 = f4_add_shfl(a0, d_);
        a1 = f4_add_shfl(a1, d_);
        a2 = f4_add_shfl(a2, d_);
        a3 = f4_add_shfl(a3, d_);
    }
    float inv = 1.0f / (s + 1e-16f);
    float4 o0 = leaky4(f4_scale(a0, inv));
    float4 o1 = leaky4(f4_scale(a1, inv));
    float4 o2 = leaky4(f4_scale(a2, inv));
    float4 o3 = leaky4(f4_scale(a3, inv));
    if (l < 4) {
        float4 oq = (l == 0) ? o0 : (l == 1) ? o1 : (l == 2) ? o2 : o3;
        if (fp8_out) {
            float ss = dot4(o0, o0) + dot4(o1, o1) + dot4(o2, o2) + dot4(o3, o3);
            float nn = fmaxf(sqrtf(ss), 1e-12f);
            char* rp = (char*)out + (size_t)i * RSTRIDE;
            ((unsigned*)rp)[l] = enc4(f4_scale(oq, 1.0f / nn));
            if (l == 0) *(float*)(rp + 16) = nn;
        } else {
            store_h4((__half*)out + (size_t)i * 16, l, oq);
        }
    }
}

// ---------------- MLP head + fused per-block logsumexp partials ----------------
// Row gathers as 2x uint4 (halves gather instructions vs 4x float2 per row).
__global__ void k_mlp(const __half* __restrict__ x, const int* __restrict__ home,
                      const int* __restrict__ away,
                      const float* __restrict__ w0, const float* __restrict__ b0,
                      const float* __restrict__ w1, const float* __restrict__ b1,
                      const float* __restrict__ w2, const float* __restrict__ b2,
                      float* __restrict__ z, float* __restrict__ bmax,
                      float* __restrict__ bsum, int nb) {
    __shared__ float sw0[192], sw1[96], sw2[48], sb0[6], sb1[16], sb2[3];
    __shared__ float rmax[4][3];
    __shared__ float rsum[4][3];
    int t = threadIdx.x;
    if (t < 192) sw0[t] = w0[t];
    if (t < 96)  sw1[t] = w1[t];
    if (t < 48)  sw2[t] = w2[t];
    if (t < 6)   sb0[t] = b0[t];
    if (t < 16)  sb1[t] = b1[t];
    if (t < 3)   sb2[t] = b2[t];
    __syncthreads();
    int i = blockIdx.x * blockDim.x + t;
    bool act = i < nb;
    float z0 = -3.4e38f, z1 = -3.4e38f, z2 = -3.4e38f;
    if (act) {
        float h[32];
        const uint4* hr = (const uint4*)(x + (size_t)home[i] * 16);
        const uint4* ar = (const uint4*)(x + (size_t)away[i] * 16);
        uint4 hv0 = hr[0], hv1 = hr[1];
        uint4 av0 = ar[0], av1 = ar[1];
        union { uint4 u; __half2 h2[4]; } cv;
#pragma unroll
        for (int q = 0; q < 4; ++q) {
            cv.u = (q == 0) ? hv0 : (q == 1) ? hv1 : (q == 2) ? av0 : av1;
#pragma unroll
            for (int k = 0; k < 4; ++k) {
                float2 f = __half22float2(cv.h2[k]);
                h[q * 8 + 2 * k + 0] = f.x;
                h[q * 8 + 2 * k + 1] = f.y;
            }
        }
        float t0[6];
#pragma unroll
        for (int o = 0; o < 6; ++o) {
            float acc = sb0[o];
#pragma unroll
            for (int k = 0; k < 32; ++k) acc = fmaf(h[k], sw0[k * 6 + o], acc);
            t0[o] = leaky_relu(acc);
        }
        float t1[16];
#pragma unroll
        for (int o = 0; o < 16; ++o) {
            float acc = sb1[o];
#pragma unroll
            for (int k = 0; k < 6; ++k) acc = fmaf(t0[k], sw1[k * 16 + o], acc);
            t1[o] = leaky_relu(acc);
        }
        float zz[3];
#pragma unroll
        for (int o = 0; o < 3; ++o) {
            float acc = sb2[o];
#pragma unroll
            for (int k = 0; k < 16; ++k) acc = fmaf(t1[k], sw2[k * 3 + o], acc);
            zz[o] = leaky_relu(acc);
            z[(size_t)i * 3 + o] = zz[o];
        }
        z0 = zz[0]; z1 = zz[1]; z2 = zz[2];
    }
    float w0_ = z0, w1_ = z1, w2_ = z2;
#pragma unroll
    for (int off = 32; off > 0; off >>= 1) {
        w0_ = fmaxf(w0_, __shfl_down(w0_, off));
        w1_ = fmaxf(w1_, __shfl_down(w1_, off));
        w2_ = fmaxf(w2_, __shfl_down(w2_, off));
    }
    int wid = t >> 6;
    if ((t & 63) == 0) { rmax[wid][0] = w0_; rmax[wid][1] = w1_; rmax[wid][2] = w2_; }
    __syncthreads();
    float M0 = fmaxf(fmaxf(rmax[0][0], rmax[1][0]), fmaxf(rmax[2][0], rmax[3][0]));
    float M1 = fmaxf(fmaxf(rmax[0][1], rmax[1][1]), fmaxf(rmax[2][1], rmax[3][1]));
    float M2 = fmaxf(fmaxf(rmax[0][2], rmax[1][2]), fmaxf(rmax[2][2], rmax[3][2]));
    float e0 = act ? __expf(z0 - M0) : 0.0f;
    float e1 = act ? __expf(z1 - M1) : 0.0f;
    float e2 = act ? __expf(z2 - M2) : 0.0f;
#pragma unroll
    for (int off = 32; off > 0; off >>= 1) {
        e0 += __shfl_down(e0, off);
        e1 += __shfl_down(e1, off);
        e2 += __shfl_down(e2, off);
    }
    if ((t & 63) == 0) { rsum[wid][0] = e0; rsum[wid][1] = e1; rsum[wid][2] = e2; }
    __syncthreads();
    if (t == 0) {
        float S0 = rsum[0][0] + rsum[1][0] + rsum[2][0] + rsum[3][0];
        float S1 = rsum[0][1] + rsum[1][1] + rsum[2][1] + rsum[3][1];
        float S2 = rsum[0][2] + rsum[1][2] + rsum[2][2] + rsum[3][2];
        bmax[blockIdx.x * 3 + 0] = M0; bmax[blockIdx.x * 3 + 1] = M1; bmax[blockIdx.x * 3 + 2] = M2;
        bsum[blockIdx.x * 3 + 0] = S0; bsum[blockIdx.x * 3 + 1] = S1; bsum[blockIdx.x * 3 + 2] = S2;
    }
}

// merge per-block (max, sumexp) partials -> global per-column
__global__ void k_lse(const float* __restrict__ bmax, const float* __restrict__ bsum,
                      float* __restrict__ gM, float* __restrict__ gS, int nblk) {
    __shared__ float lm[4][3];
    __shared__ float ls[4][3];
    int t = threadIdx.x;
    float M0 = -3.4e38f, M1 = -3.4e38f, M2 = -3.4e38f;
    float S0 = 0.f, S1 = 0.f, S2 = 0.f;
    for (int b = t; b < nblk; b += 256) {
        float m0 = bmax[b * 3 + 0], s0 = bsum[b * 3 + 0];
        float n0 = fmaxf(M0, m0); S0 = S0 * __expf(M0 - n0) + s0 * __expf(m0 - n0); M0 = n0;
        float m1 = bmax[b * 3 + 1], s1 = bsum[b * 3 + 1];
        float n1 = fmaxf(M1, m1); S1 = S1 * __expf(M1 - n1) + s1 * __expf(m1 - n1); M1 = n1;
        float m2 = bmax[b * 3 + 2], s2 = bsum[b * 3 + 2];
        float n2 = fmaxf(M2, m2); S2 = S2 * __expf(M2 - n2) + s2 * __expf(m2 - n2); M2 = n2;
    }
#pragma unroll
    for (int off = 32; off > 0; off >>= 1) {
        float mo, so, nm;
        mo = __shfl_down(M0, off); so = __shfl_down(S0, off);
        nm = fmaxf(M0, mo); S0 = S0 * __expf(M0 - nm) + so * __expf(mo - nm); M0 = nm;
        mo = __shfl_down(M1, off); so = __shfl_down(S1, off);
        nm = fmaxf(M1, mo); S1 = S1 * __expf(M1 - nm) + so * __expf(mo - nm); M1 = nm;
        mo = __shfl_down(M2, off); so = __shfl_down(S2, off);
        nm = fmaxf(M2, mo); S2 = S2 * __expf(M2 - nm) + so * __expf(mo - nm); M2 = nm;
    }
    int wid = t >> 6;
    if ((t & 63) == 0) {
        lm[wid][0] = M0; lm[wid][1] = M1; lm[wid][2] = M2;
        ls[wid][0] = S0; ls[wid][1] = S1; ls[wid][2] = S2;
    }
    __syncthreads();
    if (t == 0) {
        for (int w = 1; w < 4; ++w) {
            float nm;
            nm = fmaxf(M0, lm[w][0]); S0 = S0 * __expf(M0 - nm) + ls[w][0] * __expf(lm[w][0] - nm); M0 = nm;
            nm = fmaxf(M1, lm[w][1]); S1 = S1 * __expf(M1 - nm) + ls[w][1] * __expf(lm[w][1] - nm); M1 = nm;
            nm = fmaxf(M2, lm[w][2]); S2 = S2 * __expf(M2 - nm) + ls[w][2] * __expf(lm[w][2] - nm); M2 = nm;
        }
        gM[0] = M0; gM[1] = M1; gM[2] = M2;
        gS[0] = S0; gS[1] = S1; gS[2] = S2;
    }
}

__device__ __forceinline__ float pick3(int c, float L0, float L1, float L2) {
    return c == 0 ? L0 : (c == 1 ? L1 : L2);
}

// vectorized: 4 floats/thread; component column = (4i+k) % 3
__global__ void k_final(const float4* __restrict__ z4, const float* __restrict__ gM,
                        const float* __restrict__ gS, float4* __restrict__ out4, int n4) {
    int i = blockIdx.x * blockDim.x + threadIdx.x;
    if (i >= n4) return;
    float L0 = gM[0] + logf(gS[0]);
    float L1 = gM[1] + logf(gS[1]);
    float L2 = gM[2] + logf(gS[2]);
    float4 v = z4[i];
    int c = i % 3;                 // (4i)%3 == i%3
    int c1 = (c + 1) % 3, c2 = (c + 2) % 3;
    out4[i] = make_float4(v.x - pick3(c, L0, L1, L2),
                          v.y - pick3(c1, L0, L1, L2),
                          v.z - pick3(c2, L0, L1, L2),
                          v.w - pick3(c, L0, L1, L2));
}

extern "C" void kernel_launch(void* const* d_in, const int* in_sizes, int n_in,
                              void* d_out, int out_size, void* d_ws, size_t ws_size,
                              hipStream_t stream) {
    const float* embed = (const float*)d_in[0];
    const float* beta  = (const float*)d_in[1];
    const float* w0 = (const float*)d_in[2];
    const float* b0 = (const float*)d_in[3];
    const float* w1 = (const float*)d_in[4];
    const float* b1 = (const float*)d_in[5];
    const float* w2 = (const float*)d_in[6];
    const float* b2 = (const float*)d_in[7];
    const int* eidx = (const int*)d_in[8];
    const int* home = (const int*)d_in[9];
    const int* away = (const int*)d_in[10];

    const int N = in_sizes[0] / 16;
    const int E = in_sizes[8] / 2;
    const int B = in_sizes[9];
    const int* esrc = eidx;
    const int* edst = eidx + E;
    const int K = (N + NPB - 1) >> NPB_SHIFT;       // 391 buckets
    const int NC = (E + EPB - 1) / EPB;             // 391 chunks (<=512)

    char* ws = (char*)d_ws;
    size_t off = 0;
    auto alloc = [&](size_t bytes) -> char* {
        off = (off + 255) & ~(size_t)255;
        char* p = ws + off;
        off += bytes;
        return p;
    };
    // union region: bdata (build) aliases {xqn1, zbuf} (both written after binB)
    size_t bdata_bytes = (size_t)NC * EPB * 4;   // 12.8 MB
    size_t alias_bytes = (((size_t)N * RSTRIDE + 511) & ~(size_t)255) + (size_t)B * 3 * 4;
    char* U = alloc(bdata_bytes > alias_bytes ? bdata_bytes : alias_bytes);
    unsigned* bdata = (unsigned*)U;
    char* xqn1  = U;                                                        // N*32B packed
    float* zbuf = (float*)(U + (((size_t)N * RSTRIDE + 511) & ~(size_t)255)); // B*3*4B

    int* startp  = (int*)alloc((size_t)N * 4);
    int* endp    = (int*)alloc((size_t)N * 4);
    int* colw    = (int*)alloc((size_t)K * BCAP * 4);   // padded per-bucket windows
    int* cbase   = (int*)alloc((size_t)NC * K * 4);
    int* ccnt    = (int*)alloc((size_t)NC * K * 4);
    char* xqn0   = alloc((size_t)N * RSTRIDE);
    __half* xh2  = (__half*)alloc((size_t)N * 32);
    const int nblkB = (B + TPB - 1) / TPB;
    float* bmax  = (float*)alloc((size_t)nblkB * 3 * 4);
    float* bsum  = (float*)alloc((size_t)nblkB * 3 * 4);
    float* gM    = (float*)alloc(16);
    float* gS    = (float*)alloc(16);
    (void)ws_size; (void)n_in; (void)out_size;

    k_binA<<<NC, 512, 0, stream>>>(esrc, edst, bdata, cbase, ccnt, E, K,
                                   embed, xqn0, N);
    k_binB<<<K, 512, 0, stream>>>(bdata, cbase, ccnt, startp, endp, colw, N, NC, K);

    const int nblkN8 = (N + 63) / 64;   // 512 threads, 8 lanes/node
    k_agnn<<<nblkN8, 512, 0, stream>>>(xqn0, startp, endp, colw, beta, 0, xqn1, N, 1);
    k_agnn<<<nblkN8, 512, 0, stream>>>(xqn1, startp, endp, colw, beta, 1, xh2, N, 0);

    k_mlp<<<nblkB, TPB, 0, stream>>>(xh2, home, away, w0, b0, w1, b1, w2, b2,
                                     zbuf, bmax, bsum, B);
    k_lse<<<1, 256, 0, stream>>>(bmax, bsum, gM, gS, nblkB);
    const int n4 = (B * 3) / 4;
    k_final<<<(n4 + TPB - 1) / TPB, TPB, 0, stream>>>((const float4*)zbuf, gM, gS,
                                                      (float4*)d_out, n4);
}